// Round 12
// baseline (138.081 us; speedup 1.0000x reference)
//
#include <hip/hip_runtime.h>
#include <stdint.h>

#define HIDDEN 1024
#define HEADS  16
#define DK     64
#define BATCH  2
#define SEQ    2048
#define MTOT   (BATCH*SEQ)
#define QSCALE 0.1803368801111204f  /* log2(e)/8 : folds softmax scale + exp2 conversion into Q */

typedef float  f32x4   __attribute__((ext_vector_type(4)));
typedef float  f32x16  __attribute__((ext_vector_type(16)));
typedef __bf16 bf16x8  __attribute__((ext_vector_type(8)));

__device__ __forceinline__ unsigned short f2bf(float f) {
    union { float f; uint32_t u; } x;
    x.f = f;
    uint32_t r = x.u + 0x7fffu + ((x.u >> 16) & 1u);
    return (unsigned short)(r >> 16);
}

__device__ __forceinline__ bf16x8 ld_bf8(const unsigned short* p) {
    return *reinterpret_cast<const bf16x8*>(p);
}

__device__ __forceinline__ void gload16(const void* g, void* l) {
    __builtin_amdgcn_global_load_lds(
        (const __attribute__((address_space(1))) void*)g,
        (__attribute__((address_space(3))) void*)l, 16, 0, 0);
}

__device__ __forceinline__ uint32_t pkbf(float a, float b) {
    union { __bf16 h[2]; uint32_t u; } pk;
    pk.h[0] = (__bf16)a; pk.h[1] = (__bf16)b;
    return pk.u;
}

__device__ __forceinline__ float tsum16(const f32x16& v) {
    float a = (v[0] + v[1]) + (v[2] + v[3]);
    float b = (v[4] + v[5]) + (v[6] + v[7]);
    float c = (v[8] + v[9]) + (v[10] + v[11]);
    float d = (v[12] + v[13]) + (v[14] + v[15]);
    return (a + b) + (c + d);
}

// ---------------- fused fp32 -> bf16 convert for all 7 tensors ----------------
struct Cvt7 {
    const float* s[7];
    unsigned short* d[7];
    int n8[7];
};
__global__ __launch_bounds__(256) void cvt_all(Cvt7 a) {
    int id = blockIdx.y;
    int i = blockIdx.x * blockDim.x + threadIdx.x;
    if (i >= a.n8[id]) return;
    const float4* s = reinterpret_cast<const float4*>(a.s[id]) + (size_t)i * 2;
    float4 x = s[0], y = s[1];
    union { unsigned short us[8]; uint4 v; } o;
    o.us[0] = f2bf(x.x); o.us[1] = f2bf(x.y); o.us[2] = f2bf(x.z); o.us[3] = f2bf(x.w);
    o.us[4] = f2bf(y.x); o.us[5] = f2bf(y.y); o.us[6] = f2bf(y.z); o.us[7] = f2bf(y.w);
    reinterpret_cast<uint4*>(a.d[id])[i] = o.v;
}

// ---------------- GEMM body v5: SINGLE-buffered 32 KB LDS (m97-faithful) ----------------
// R11's explicit double-buffer (64 KB LDS) capped residency at 2 blocks/CU — m132's
// regression regime (~500 TF). Single buffer restores ~4 blocks/CU; cross-block wave
// overlap (m114) hides staging latency + barrier drain. XOR swizzle + XCD swizzle kept.
__device__ __forceinline__ void gemm_body(const unsigned short* __restrict__ A,
                                          const unsigned short* __restrict__ W,
                                          const float* __restrict__ bias,
                                          void* __restrict__ out, int mode, float scale,
                                          int bm, int bn) {
    __shared__ __align__(16) unsigned short Alds[128 * 64];
    __shared__ __align__(16) unsigned short Blds[128 * 64];
    const int t    = threadIdx.x;
    const int lane = t & 63;
    const int wid  = t >> 6;
    const int wm   = (wid >> 1) * 64;
    const int wn   = (wid & 1) * 64;
    const int fr   = lane & 15;
    const int fg   = lane >> 4;
    const int K    = HIDDEN;

    f32x4 acc[4][4];
#pragma unroll
    for (int i = 0; i < 4; i++)
#pragma unroll
        for (int j = 0; j < 4; j++) acc[i][j] = (f32x4){0.f, 0.f, 0.f, 0.f};

    const int seg_row = t >> 3;
    const int seg_col = ((t & 7) ^ (seg_row & 7)) * 8;   // inverse-swizzled source granule
    const int ldst    = (t & ~63) * 8;                   // linear LDS dest (shorts)

    const unsigned short* ga = A + (size_t)(bm * 128 + seg_row) * K + seg_col;
    const unsigned short* gb = W + (size_t)(bn * 128 + seg_row) * K + seg_col;

    for (int ks = 0; ks < K / 64; ++ks) {
        const int k0 = ks * 64;
#pragma unroll
        for (int i = 0; i < 4; i++) {
            gload16(ga + (size_t)(i * 32) * K + k0, &Alds[i * 2048 + ldst]);
            gload16(gb + (size_t)(i * 32) * K + k0, &Blds[i * 2048 + ldst]);
        }
        __syncthreads();   // drains vmcnt: staged tile visible
#pragma unroll
        for (int kk = 0; kk < 2; kk++) {
            bf16x8 af[4], bf[4];
#pragma unroll
            for (int mt = 0; mt < 4; mt++)
                af[mt] = ld_bf8(&Alds[(wm + mt * 16 + fr) * 64 +
                                      (((kk * 4 + fg) ^ (fr & 7)) * 8)]);
#pragma unroll
            for (int nt = 0; nt < 4; nt++)
                bf[nt] = ld_bf8(&Blds[(wn + nt * 16 + fr) * 64 +
                                      (((kk * 4 + fg) ^ (fr & 7)) * 8)]);
#pragma unroll
            for (int mt = 0; mt < 4; mt++)
#pragma unroll
                for (int nt = 0; nt < 4; nt++)
                    acc[mt][nt] = __builtin_amdgcn_mfma_f32_16x16x32_bf16(
                        af[mt], bf[nt], acc[mt][nt], 0, 0, 0);
        }
        __syncthreads();   // all reads done before next stage overwrites
    }

    const int base_row = bm * 128 + wm + fg * 4;
    const int base_col = bn * 128 + wn + fr;
#pragma unroll
    for (int mt = 0; mt < 4; mt++) {
#pragma unroll
        for (int nt = 0; nt < 4; nt++) {
            int col = base_col + nt * 16;
            float bv = bias[col];
#pragma unroll
            for (int e = 0; e < 4; e++) {
                int row = base_row + mt * 16 + e;
                float val = (acc[mt][nt][e] + bv) * scale;
                if (mode == 2) {
                    ((float*)out)[(size_t)row * HIDDEN + col] = val;
                } else {
                    int b = row >> 11, s = row & (SEQ - 1);
                    int h = col >> 6, d = col & (DK - 1);
                    size_t idx;
                    if (mode == 0)
                        idx = ((size_t)(b * HEADS + h) * SEQ + s) * DK + d;
                    else
                        idx = ((size_t)(b * HEADS + h) * DK + d) * SEQ + s;
                    ((unsigned short*)out)[idx] = f2bf(val);
                }
            }
        }
    }
}

// Bijective XCD-chunked remap: 256 blocks, 8 XCDs, chunk = 4bm x 8bn (256%8==0, ERRATA#11 ok).
__device__ __forceinline__ void xcd_swz(int bx, int by, int& bm, int& bn) {
    int lin = by * 8 + bx;
    int xcd = lin & 7;
    int idx = lin >> 3;
    bm = xcd * 4 + (idx >> 3);
    bn = idx & 7;
}

__global__ __launch_bounds__(256) void gemm_qkv(
    const unsigned short* __restrict__ qbf, const unsigned short* __restrict__ kbf,
    const unsigned short* __restrict__ vbf, const unsigned short* __restrict__ wq,
    const unsigned short* __restrict__ wk, const unsigned short* __restrict__ wv,
    const float* __restrict__ bq, const float* __restrict__ bk,
    const float* __restrict__ bv, unsigned short* __restrict__ qh,
    unsigned short* __restrict__ kh, unsigned short* __restrict__ vt) {
    int z = blockIdx.z;
    const unsigned short* A = (z == 0) ? qbf : (z == 1) ? kbf : vbf;
    const unsigned short* W = (z == 0) ? wq : (z == 1) ? wk : wv;
    const float* bias       = (z == 0) ? bq : (z == 1) ? bk : bv;
    unsigned short* out     = (z == 0) ? qh : (z == 1) ? kh : vt;
    int bm, bn;
    xcd_swz(blockIdx.x, blockIdx.y, bm, bn);
    gemm_body(A, W, bias, out, (z == 2) ? 1 : 0, (z == 0) ? QSCALE : 1.0f, bm, bn);
}

__global__ __launch_bounds__(256) void gemm_out(const unsigned short* __restrict__ ctx,
                                                const unsigned short* __restrict__ wo,
                                                const float* __restrict__ bo,
                                                float* __restrict__ out) {
    int bm, bn;
    xcd_swz(blockIdx.x, blockIdx.y, bm, bn);
    gemm_body(ctx, wo, bo, out, 2, 1.0f, bm, bn);
}

// ---------------- flash attention v8 (unchanged from round 10/11, passing) ----------------
__global__ __launch_bounds__(512, 2) void attn_kernel(const unsigned short* __restrict__ qh,
                                                      const unsigned short* __restrict__ kh,
                                                      const unsigned short* __restrict__ vt,
                                                      unsigned short* __restrict__ ctx) {
    const int t = threadIdx.x, lane = t & 63, w = t >> 6;
    const int lo = lane & 31, hi = lane >> 5;
    const int qsub = w & 3, split = w >> 2;
    const int id = blockIdx.x;
    const int g  = (id & 7) * 32 + (id >> 3);   // XCD-chunked: 4 heads per XCD
    const int by = g >> 3;                       // head-batch 0..31
    const int bx = g & 7;                        // 256-row q block 0..7
    const size_t hb = (size_t)by * (SEQ * DK);
    const int q0a = bx * 256 + qsub * 32;
    const int q0b = q0a + 128;

    struct KV { unsigned short K[2][2][64 * 64]; unsigned short V[2][2][64 * 64]; };
    struct MG { float Lo[4][2][32][64]; float Ll[4][2][64]; };
    __shared__ union SMem { KV kv; MG mg; } sm;

    const unsigned short* sp[4];
    unsigned short* dpK[4];
    int sstr[4];
#pragma unroll
    for (int i = 0; i < 4; ++i) {
        int u   = w * 4 + i;
        int isV = u >> 4;
        int ssp = (u >> 3) & 1;
        int r0  = (u & 7) * 8;
        int rl  = r0 + (lane >> 3);
        int cs  = ((lane & 7) ^ ((lane >> 3) & 7)) * 8;
        if (!isV) {
            sp[i]   = kh + hb + (size_t)(ssp * 1024 + rl) * DK + cs;
            sstr[i] = 64 * DK;
            dpK[i]  = &sm.kv.K[0][ssp][r0 * 64];
        } else {
            sp[i]   = vt + hb + (size_t)rl * SEQ + ssp * 1024 + cs;
            sstr[i] = 64;
            dpK[i]  = &sm.kv.V[0][ssp][r0 * 64];
        }
    }
    const int bufoff = 2 * 64 * 64;

    bf16x8 qfA[4], qfB[4];
#pragma unroll
    for (int tl = 0; tl < 4; ++tl) {
        qfA[tl] = ld_bf8(&qh[hb + (size_t)(q0a + lo) * DK + tl * 16 + hi * 8]);
        qfB[tl] = ld_bf8(&qh[hb + (size_t)(q0b + lo) * DK + tl * 16 + hi * 8]);
    }

    f32x16 o0a, o1a, o0b, o1b;
#pragma unroll
    for (int e = 0; e < 16; ++e) { o0a[e] = 0.f; o1a[e] = 0.f; o0b[e] = 0.f; o1b[e] = 0.f; }
    float lA = 0.f, lB = 0.f;

#pragma unroll
    for (int i = 0; i < 4; ++i) { gload16(sp[i], dpK[i]); sp[i] += sstr[i]; }
    __syncthreads();

    const int xr = lo & 7;

    for (int it = 0; it < 16; ++it) {
        const unsigned short* Kb = &sm.kv.K[it & 1][split][0];
        const unsigned short* Vb = &sm.kv.V[it & 1][split][0];
        if (it < 15) {
#pragma unroll
            for (int i = 0; i < 4; ++i) {
                unsigned short* d = dpK[i] + ((it & 1) ? 0 : bufoff);
                gload16(sp[i], d);
                sp[i] += sstr[i];
            }
        }
        // =============== STREAM A ===============
        f32x16 sA, sB;
#pragma unroll
        for (int e = 0; e < 16; ++e) { sA[e] = 0.f; sB[e] = 0.f; }
        __builtin_amdgcn_s_setprio(1);
#pragma unroll
        for (int tl = 0; tl < 4; ++tl) {
            int c = 2 * tl + hi;
            bf16x8 kfA = ld_bf8(&Kb[lo * 64 + ((c ^ xr) * 8)]);
            bf16x8 kfB = ld_bf8(&Kb[(32 + lo) * 64 + ((c ^ xr) * 8)]);
            sA = __builtin_amdgcn_mfma_f32_32x32x16_bf16(kfA, qfA[tl], sA, 0, 0, 0);
            sB = __builtin_amdgcn_mfma_f32_32x32x16_bf16(kfB, qfA[tl], sB, 0, 0, 0);
        }
        __builtin_amdgcn_s_setprio(0);
#pragma unroll
        for (int e = 0; e < 16; ++e) {
            sA[e] = __builtin_amdgcn_exp2f(sA[e]);
            sB[e] = __builtin_amdgcn_exp2f(sB[e]);
        }
        {
            float sum = tsum16(sA) + tsum16(sB);
            sum += __shfl_xor(sum, 32);
            lA += sum;
        }
        {
            uint32_t pA[8], pB[8];
#pragma unroll
            for (int i = 0; i < 8; ++i) {
                pA[i] = pkbf(sA[2 * i], sA[2 * i + 1]);
                pB[i] = pkbf(sB[2 * i], sB[2 * i + 1]);
            }
            asm volatile("v_permlane32_swap_b32 %0, %1" : "+v"(pA[0]), "+v"(pA[2]));
            asm volatile("v_permlane32_swap_b32 %0, %1" : "+v"(pA[1]), "+v"(pA[3]));
            asm volatile("v_permlane32_swap_b32 %0, %1" : "+v"(pA[4]), "+v"(pA[6]));
            asm volatile("v_permlane32_swap_b32 %0, %1" : "+v"(pA[5]), "+v"(pA[7]));
            asm volatile("v_permlane32_swap_b32 %0, %1" : "+v"(pB[0]), "+v"(pB[2]));
            asm volatile("v_permlane32_swap_b32 %0, %1" : "+v"(pB[1]), "+v"(pB[3]));
            asm volatile("v_permlane32_swap_b32 %0, %1" : "+v"(pB[4]), "+v"(pB[6]));
            asm volatile("v_permlane32_swap_b32 %0, %1" : "+v"(pB[5]), "+v"(pB[7]));
            union { uint32_t u[4]; bf16x8 v; } f0, f1, f2, f3;
            f0.u[0] = pA[0]; f0.u[1] = pA[1]; f0.u[2] = pA[2]; f0.u[3] = pA[3];
            f1.u[0] = pA[4]; f1.u[1] = pA[5]; f1.u[2] = pA[6]; f1.u[3] = pA[7];
            f2.u[0] = pB[0]; f2.u[1] = pB[1]; f2.u[2] = pB[2]; f2.u[3] = pB[3];
            f3.u[0] = pB[4]; f3.u[1] = pB[5]; f3.u[2] = pB[6]; f3.u[3] = pB[7];
            bf16x8 v00 = ld_bf8(&Vb[lo * 64 + (((0 + hi) ^ xr) * 8)]);
            bf16x8 v01 = ld_bf8(&Vb[lo * 64 + (((2 + hi) ^ xr) * 8)]);
            bf16x8 v02 = ld_bf8(&Vb[lo * 64 + (((4 + hi) ^ xr) * 8)]);
            bf16x8 v03 = ld_bf8(&Vb[lo * 64 + (((6 + hi) ^ xr) * 8)]);
            bf16x8 v10 = ld_bf8(&Vb[(32 + lo) * 64 + (((0 + hi) ^ xr) * 8)]);
            bf16x8 v11 = ld_bf8(&Vb[(32 + lo) * 64 + (((2 + hi) ^ xr) * 8)]);
            bf16x8 v12 = ld_bf8(&Vb[(32 + lo) * 64 + (((4 + hi) ^ xr) * 8)]);
            bf16x8 v13 = ld_bf8(&Vb[(32 + lo) * 64 + (((6 + hi) ^ xr) * 8)]);
            __builtin_amdgcn_s_setprio(1);
            o0a = __builtin_amdgcn_mfma_f32_32x32x16_bf16(v00, f0.v, o0a, 0, 0, 0);
            o0a = __builtin_amdgcn_mfma_f32_32x32x16_bf16(v01, f1.v, o0a, 0, 0, 0);
            o0a = __builtin_amdgcn_mfma_f32_32x32x16_bf16(v02, f2.v, o0a, 0, 0, 0);
            o0a = __builtin_amdgcn_mfma_f32_32x32x16_bf16(v03, f3.v, o0a, 0, 0, 0);
            o1a = __builtin_amdgcn_mfma_f32_32x32x16_bf16(v10, f0.v, o1a, 0, 0, 0);
            o1a = __builtin_amdgcn_mfma_f32_32x32x16_bf16(v11, f1.v, o1a, 0, 0, 0);
            o1a = __builtin_amdgcn_mfma_f32_32x32x16_bf16(v12, f2.v, o1a, 0, 0, 0);
            o1a = __builtin_amdgcn_mfma_f32_32x32x16_bf16(v13, f3.v, o1a, 0, 0, 0);
            __builtin_amdgcn_s_setprio(0);
        }
        // =============== STREAM B ===============
#pragma unroll
        for (int e = 0; e < 16; ++e) { sA[e] = 0.f; sB[e] = 0.f; }
        __builtin_amdgcn_s_setprio(1);
#pragma unroll
        for (int tl = 0; tl < 4; ++tl) {
            int c = 2 * tl + hi;
            bf16x8 kfA = ld_bf8(&Kb[lo * 64 + ((c ^ xr) * 8)]);
            bf16x8 kfB = ld_bf8(&Kb[(32 + lo) * 64 + ((c ^ xr) * 8)]);
            sA = __builtin_amdgcn_mfma_f32_32x32x16_bf16(kfA, qfB[tl], sA, 0, 0, 0);
            sB = __builtin_amdgcn_mfma_f32_32x32x16_bf16(kfB, qfB[tl], sB, 0, 0, 0);
        }
        __builtin_amdgcn_s_setprio(0);
#pragma unroll
        for (int e = 0; e < 16; ++e) {
            sA[e] = __builtin_amdgcn_exp2f(sA[e]);
            sB[e] = __builtin_amdgcn_exp2f(sB[e]);
        }
        {
            float sum = tsum16(sA) + tsum16(sB);
            sum += __shfl_xor(sum, 32);
            lB += sum;
        }
        {
            uint32_t pA[8], pB[8];
#pragma unroll
            for (int i = 0; i < 8; ++i) {
                pA[i] = pkbf(sA[2 * i], sA[2 * i + 1]);
                pB[i] = pkbf(sB[2 * i], sB[2 * i + 1]);
            }
            asm volatile("v_permlane32_swap_b32 %0, %1" : "+v"(pA[0]), "+v"(pA[2]));
            asm volatile("v_permlane32_swap_b32 %0, %1" : "+v"(pA[1]), "+v"(pA[3]));
            asm volatile("v_permlane32_swap_b32 %0, %1" : "+v"(pA[4]), "+v"(pA[6]));
            asm volatile("v_permlane32_swap_b32 %0, %1" : "+v"(pA[5]), "+v"(pA[7]));
            asm volatile("v_permlane32_swap_b32 %0, %1" : "+v"(pB[0]), "+v"(pB[2]));
            asm volatile("v_permlane32_swap_b32 %0, %1" : "+v"(pB[1]), "+v"(pB[3]));
            asm volatile("v_permlane32_swap_b32 %0, %1" : "+v"(pB[4]), "+v"(pB[6]));
            asm volatile("v_permlane32_swap_b32 %0, %1" : "+v"(pB[5]), "+v"(pB[7]));
            union { uint32_t u[4]; bf16x8 v; } f0, f1, f2, f3;
            f0.u[0] = pA[0]; f0.u[1] = pA[1]; f0.u[2] = pA[2]; f0.u[3] = pA[3];
            f1.u[0] = pA[4]; f1.u[1] = pA[5]; f1.u[2] = pA[6]; f1.u[3] = pA[7];
            f2.u[0] = pB[0]; f2.u[1] = pB[1]; f2.u[2] = pB[2]; f2.u[3] = pB[3];
            f3.u[0] = pB[4]; f3.u[1] = pB[5]; f3.u[2] = pB[6]; f3.u[3] = pB[7];
            bf16x8 v00 = ld_bf8(&Vb[lo * 64 + (((0 + hi) ^ xr) * 8)]);
            bf16x8 v01 = ld_bf8(&Vb[lo * 64 + (((2 + hi) ^ xr) * 8)]);
            bf16x8 v02 = ld_bf8(&Vb[lo * 64 + (((4 + hi) ^ xr) * 8)]);
            bf16x8 v03 = ld_bf8(&Vb[lo * 64 + (((6 + hi) ^ xr) * 8)]);
            bf16x8 v10 = ld_bf8(&Vb[(32 + lo) * 64 + (((0 + hi) ^ xr) * 8)]);
            bf16x8 v11 = ld_bf8(&Vb[(32 + lo) * 64 + (((2 + hi) ^ xr) * 8)]);
            bf16x8 v12 = ld_bf8(&Vb[(32 + lo) * 64 + (((4 + hi) ^ xr) * 8)]);
            bf16x8 v13 = ld_bf8(&Vb[(32 + lo) * 64 + (((6 + hi) ^ xr) * 8)]);
            __builtin_amdgcn_s_setprio(1);
            o0b = __builtin_amdgcn_mfma_f32_32x32x16_bf16(v00, f0.v, o0b, 0, 0, 0);
            o0b = __builtin_amdgcn_mfma_f32_32x32x16_bf16(v01, f1.v, o0b, 0, 0, 0);
            o0b = __builtin_amdgcn_mfma_f32_32x32x16_bf16(v02, f2.v, o0b, 0, 0, 0);
            o0b = __builtin_amdgcn_mfma_f32_32x32x16_bf16(v03, f3.v, o0b, 0, 0, 0);
            o1b = __builtin_amdgcn_mfma_f32_32x32x16_bf16(v10, f0.v, o1b, 0, 0, 0);
            o1b = __builtin_amdgcn_mfma_f32_32x32x16_bf16(v11, f1.v, o1b, 0, 0, 0);
            o1b = __builtin_amdgcn_mfma_f32_32x32x16_bf16(v12, f2.v, o1b, 0, 0, 0);
            o1b = __builtin_amdgcn_mfma_f32_32x32x16_bf16(v13, f3.v, o1b, 0, 0, 0);
            __builtin_amdgcn_s_setprio(0);
        }
        __syncthreads();
    }

    if (split == 1) {
#pragma unroll
        for (int e = 0; e < 16; ++e) {
            sm.mg.Lo[qsub][0][e][lane]      = o0a[e];
            sm.mg.Lo[qsub][0][16 + e][lane] = o1a[e];
            sm.mg.Lo[qsub][1][e][lane]      = o0b[e];
            sm.mg.Lo[qsub][1][16 + e][lane] = o1b[e];
        }
        sm.mg.Ll[qsub][0][lane] = lA;
        sm.mg.Ll[qsub][1][lane] = lB;
    }
    __syncthreads();
    if (split == 0) {
        const int b = by >> 4, hd = by & 15;
        {
            float rl = __builtin_amdgcn_rcpf(lA + sm.mg.Ll[qsub][0][lane]);
            unsigned short* orow = ctx + ((size_t)(b * SEQ + q0a + lo)) * HIDDEN + hd * 64;
#pragma unroll
            for (int dt = 0; dt < 2; ++dt) {
#pragma unroll
                for (int gq = 0; gq < 4; ++gq) {
                    union { unsigned short us[4]; uint2 v; } pk;
#pragma unroll
                    for (int c = 0; c < 4; ++c) {
                        int e = gq * 4 + c;
                        float own = dt ? o1a[e] : o0a[e];
                        float oth = sm.mg.Lo[qsub][0][dt * 16 + e][lane];
                        pk.us[c] = f2bf((own + oth) * rl);
                    }
                    *reinterpret_cast<uint2*>(orow + dt * 32 + gq * 8 + hi * 4) = pk.v;
                }
            }
        }
        {
            float rl = __builtin_amdgcn_rcpf(lB + sm.mg.Ll[qsub][1][lane]);
            unsigned short* orow = ctx + ((size_t)(b * SEQ + q0b + lo)) * HIDDEN + hd * 64;
#pragma unroll
            for (int dt = 0; dt < 2; ++dt) {
#pragma unroll
                for (int gq = 0; gq < 4; ++gq) {
                    union { unsigned short us[4]; uint2 v; } pk;
#pragma unroll
                    for (int c = 0; c < 4; ++c) {
                        int e = gq * 4 + c;
                        float own = dt ? o1b[e] : o0b[e];
                        float oth = sm.mg.Lo[qsub][1][dt * 16 + e][lane];
                        pk.us[c] = f2bf((own + oth) * rl);
                    }
                    *reinterpret_cast<uint2*>(orow + dt * 32 + gq * 8 + hi * 4) = pk.v;
                }
            }
        }
    }
}

// ---------------- launch ----------------
extern "C" void kernel_launch(void* const* d_in, const int* in_sizes, int n_in,
                              void* d_out, int out_size, void* d_ws, size_t ws_size,
                              hipStream_t stream) {
    const float* q  = (const float*)d_in[0];
    const float* k  = (const float*)d_in[1];
    const float* v  = (const float*)d_in[2];
    const float* Wq = (const float*)d_in[3];
    const float* bq = (const float*)d_in[4];
    const float* Wk = (const float*)d_in[5];
    const float* bk = (const float*)d_in[6];
    const float* Wv = (const float*)d_in[7];
    const float* bv = (const float*)d_in[8];
    const float* Wo = (const float*)d_in[9];
    const float* bo = (const float*)d_in[10];

    unsigned short* qbf = (unsigned short*)d_ws;
    unsigned short* kbf = qbf + (size_t)MTOT * HIDDEN;
    unsigned short* vbf = kbf + (size_t)MTOT * HIDDEN;
    unsigned short* wqb = vbf + (size_t)MTOT * HIDDEN;
    unsigned short* wkb = wqb + (size_t)HIDDEN * HIDDEN;
    unsigned short* wvb = wkb + (size_t)HIDDEN * HIDDEN;
    unsigned short* wob = wvb + (size_t)HIDDEN * HIDDEN;
    unsigned short* qh  = wob + (size_t)HIDDEN * HIDDEN;
    unsigned short* kh  = qh + (size_t)MTOT * HIDDEN;
    unsigned short* vt  = kh + (size_t)MTOT * HIDDEN;
    unsigned short* ctx = vt + (size_t)MTOT * HIDDEN;

    const int nAct8 = MTOT * HIDDEN / 8;    // 524288
    const int nW8   = HIDDEN * HIDDEN / 8;  // 131072

    Cvt7 ca;
    ca.s[0] = q;  ca.d[0] = qbf; ca.n8[0] = nAct8;
    ca.s[1] = k;  ca.d[1] = kbf; ca.n8[1] = nAct8;
    ca.s[2] = v;  ca.d[2] = vbf; ca.n8[2] = nAct8;
    ca.s[3] = Wq; ca.d[3] = wqb; ca.n8[3] = nW8;
    ca.s[4] = Wk; ca.d[4] = wkb; ca.n8[4] = nW8;
    ca.s[5] = Wv; ca.d[5] = wvb; ca.n8[5] = nW8;
    ca.s[6] = Wo; ca.d[6] = wob; ca.n8[6] = nW8;
    cvt_all<<<dim3(nAct8 / 256, 7), dim3(256), 0, stream>>>(ca);

    gemm_qkv<<<dim3(HIDDEN / 128, MTOT / 128, 3), dim3(256), 0, stream>>>(
        qbf, kbf, vbf, wqb, wkb, wvb, bq, bk, bv, qh, kh, vt);

    attn_kernel<<<dim3(256), dim3(512), 0, stream>>>(qh, kh, vt, ctx);

    gemm_out<<<dim3(HIDDEN / 128, MTOT / 128), dim3(256), 0, stream>>>(
        ctx, wob, bo, (float*)d_out);
}

// Round 13
// 128.461 us; speedup vs baseline: 1.0749x; 1.0749x over previous
//
#include <hip/hip_runtime.h>
#include <stdint.h>

#define HIDDEN 1024
#define HEADS  16
#define DK     64
#define BATCH  2
#define SEQ    2048
#define MTOT   (BATCH*SEQ)
#define QSCALE 0.1803368801111204f  /* log2(e)/8 : folds softmax scale + exp2 conversion into Q */

typedef float  f32x4   __attribute__((ext_vector_type(4)));
typedef float  f32x16  __attribute__((ext_vector_type(16)));
typedef __bf16 bf16x8  __attribute__((ext_vector_type(8)));

__device__ __forceinline__ unsigned short f2bf(float f) {
    union { float f; uint32_t u; } x;
    x.f = f;
    uint32_t r = x.u + 0x7fffu + ((x.u >> 16) & 1u);
    return (unsigned short)(r >> 16);
}

__device__ __forceinline__ bf16x8 ld_bf8(const unsigned short* p) {
    return *reinterpret_cast<const bf16x8*>(p);
}

__device__ __forceinline__ void gload16(const void* g, void* l) {
    __builtin_amdgcn_global_load_lds(
        (const __attribute__((address_space(1))) void*)g,
        (__attribute__((address_space(3))) void*)l, 16, 0, 0);
}

__device__ __forceinline__ uint32_t pkbf(float a, float b) {
    union { __bf16 h[2]; uint32_t u; } pk;
    pk.h[0] = (__bf16)a; pk.h[1] = (__bf16)b;
    return pk.u;
}

__device__ __forceinline__ float tsum16(const f32x16& v) {
    float a = (v[0] + v[1]) + (v[2] + v[3]);
    float b = (v[4] + v[5]) + (v[6] + v[7]);
    float c = (v[8] + v[9]) + (v[10] + v[11]);
    float d = (v[12] + v[13]) + (v[14] + v[15]);
    return (a + b) + (c + d);
}

// ---------------- fused fp32 -> bf16 convert for all 7 tensors ----------------
struct Cvt7 {
    const float* s[7];
    unsigned short* d[7];
    int n8[7];
};
__global__ __launch_bounds__(256) void cvt_all(Cvt7 a) {
    int id = blockIdx.y;
    int i = blockIdx.x * blockDim.x + threadIdx.x;
    if (i >= a.n8[id]) return;
    const float4* s = reinterpret_cast<const float4*>(a.s[id]) + (size_t)i * 2;
    float4 x = s[0], y = s[1];
    union { unsigned short us[8]; uint4 v; } o;
    o.us[0] = f2bf(x.x); o.us[1] = f2bf(x.y); o.us[2] = f2bf(x.z); o.us[3] = f2bf(x.w);
    o.us[4] = f2bf(y.x); o.us[5] = f2bf(y.y); o.us[6] = f2bf(y.z); o.us[7] = f2bf(y.w);
    reinterpret_cast<uint4*>(a.d[id])[i] = o.v;
}

// ---------------- GEMM body v6: R11 double-buffered prefetch (proven 55.6us) ----------------
// + vectorized mode-1 epilogue (4 consecutive-s bf16 packed into one 8B store).
// R12's single-buffer A/B showed LDS was NOT the occupancy limiter (13% both ways)
// and cost 7% by exposing stage latency -> dbuf restored.
__device__ __forceinline__ void gemm_body(const unsigned short* __restrict__ A,
                                          const unsigned short* __restrict__ W,
                                          const float* __restrict__ bias,
                                          void* __restrict__ out, int mode, float scale,
                                          int bm, int bn) {
    __shared__ __align__(16) unsigned short Alds[2][128 * 64];
    __shared__ __align__(16) unsigned short Blds[2][128 * 64];
    const int t    = threadIdx.x;
    const int lane = t & 63;
    const int wid  = t >> 6;
    const int wm   = (wid >> 1) * 64;
    const int wn   = (wid & 1) * 64;
    const int fr   = lane & 15;
    const int fg   = lane >> 4;
    const int K    = HIDDEN;

    f32x4 acc[4][4];
#pragma unroll
    for (int i = 0; i < 4; i++)
#pragma unroll
        for (int j = 0; j < 4; j++) acc[i][j] = (f32x4){0.f, 0.f, 0.f, 0.f};

    const int seg_row = t >> 3;
    const int seg_col = ((t & 7) ^ (seg_row & 7)) * 8;   // inverse-swizzled source granule
    const int ldst    = (t & ~63) * 8;                   // linear LDS dest (shorts)

    const unsigned short* ga = A + (size_t)(bm * 128 + seg_row) * K + seg_col;
    const unsigned short* gb = W + (size_t)(bn * 128 + seg_row) * K + seg_col;

    auto stage = [&](int k0, int buf) {
#pragma unroll
        for (int i = 0; i < 4; i++) {
            gload16(ga + (size_t)(i * 32) * K + k0, &Alds[buf][i * 2048 + ldst]);
            gload16(gb + (size_t)(i * 32) * K + k0, &Blds[buf][i * 2048 + ldst]);
        }
    };

    stage(0, 0);
    __syncthreads();

    for (int ks = 0; ks < K / 64; ++ks) {
        const int cur = ks & 1;
        if (ks < K / 64 - 1) stage((ks + 1) * 64, cur ^ 1);   // prefetch in flight during compute
#pragma unroll
        for (int kk = 0; kk < 2; kk++) {
            bf16x8 af[4], bf[4];
#pragma unroll
            for (int mt = 0; mt < 4; mt++)
                af[mt] = ld_bf8(&Alds[cur][(wm + mt * 16 + fr) * 64 +
                                           (((kk * 4 + fg) ^ (fr & 7)) * 8)]);
#pragma unroll
            for (int nt = 0; nt < 4; nt++)
                bf[nt] = ld_bf8(&Blds[cur][(wn + nt * 16 + fr) * 64 +
                                           (((kk * 4 + fg) ^ (fr & 7)) * 8)]);
#pragma unroll
            for (int mt = 0; mt < 4; mt++)
#pragma unroll
                for (int nt = 0; nt < 4; nt++)
                    acc[mt][nt] = __builtin_amdgcn_mfma_f32_16x16x32_bf16(
                        af[mt], bf[nt], acc[mt][nt], 0, 0, 0);
        }
        __syncthreads();   // drains prefetch vmcnt + guards buffer reuse (one barrier/K-step)
    }

    const int base_row = bm * 128 + wm + fg * 4;
    const int base_col = bn * 128 + wn + fr;
#pragma unroll
    for (int mt = 0; mt < 4; mt++) {
#pragma unroll
        for (int nt = 0; nt < 4; nt++) {
            int col = base_col + nt * 16;
            float bv = bias[col];
            if (mode == 1) {
                // V^T: rows are 4 consecutive tokens s..s+3 at fixed (h,d) -> one 8B store
                int row0 = base_row + mt * 16;           // multiple of 4; b,h,d constant
                int b = row0 >> 11, s = row0 & (SEQ - 1);
                int h = col >> 6, d = col & (DK - 1);
                union { unsigned short us[4]; uint2 v; } pk;
#pragma unroll
                for (int e = 0; e < 4; e++)
                    pk.us[e] = f2bf((acc[mt][nt][e] + bv) * scale);
                *reinterpret_cast<uint2*>(
                    (unsigned short*)out + ((size_t)(b * HEADS + h) * DK + d) * SEQ + s) = pk.v;
            } else {
#pragma unroll
                for (int e = 0; e < 4; e++) {
                    int row = base_row + mt * 16 + e;
                    float val = (acc[mt][nt][e] + bv) * scale;
                    if (mode == 2) {
                        ((float*)out)[(size_t)row * HIDDEN + col] = val;
                    } else {  // mode 0
                        int b = row >> 11, s = row & (SEQ - 1);
                        int h = col >> 6, d = col & (DK - 1);
                        ((unsigned short*)out)[((size_t)(b * HEADS + h) * SEQ + s) * DK + d] =
                            f2bf(val);
                    }
                }
            }
        }
    }
}

// Bijective XCD-chunked remap: 256 blocks, 8 XCDs, chunk = 4bm x 8bn (256%8==0, ERRATA#11 ok).
__device__ __forceinline__ void xcd_swz(int bx, int by, int& bm, int& bn) {
    int lin = by * 8 + bx;
    int xcd = lin & 7;
    int idx = lin >> 3;
    bm = xcd * 4 + (idx >> 3);
    bn = idx & 7;
}

__global__ __launch_bounds__(256) void gemm_qkv(
    const unsigned short* __restrict__ qbf, const unsigned short* __restrict__ kbf,
    const unsigned short* __restrict__ vbf, const unsigned short* __restrict__ wq,
    const unsigned short* __restrict__ wk, const unsigned short* __restrict__ wv,
    const float* __restrict__ bq, const float* __restrict__ bk,
    const float* __restrict__ bv, unsigned short* __restrict__ qh,
    unsigned short* __restrict__ kh, unsigned short* __restrict__ vt) {
    int z = blockIdx.z;
    const unsigned short* A = (z == 0) ? qbf : (z == 1) ? kbf : vbf;
    const unsigned short* W = (z == 0) ? wq : (z == 1) ? wk : wv;
    const float* bias       = (z == 0) ? bq : (z == 1) ? bk : bv;
    unsigned short* out     = (z == 0) ? qh : (z == 1) ? kh : vt;
    int bm, bn;
    xcd_swz(blockIdx.x, blockIdx.y, bm, bn);
    gemm_body(A, W, bias, out, (z == 2) ? 1 : 0, (z == 0) ? QSCALE : 1.0f, bm, bn);
}

__global__ __launch_bounds__(256) void gemm_out(const unsigned short* __restrict__ ctx,
                                                const unsigned short* __restrict__ wo,
                                                const float* __restrict__ bo,
                                                float* __restrict__ out) {
    int bm, bn;
    xcd_swz(blockIdx.x, blockIdx.y, bm, bn);
    gemm_body(ctx, wo, bo, out, 2, 1.0f, bm, bn);
}

// ---------------- flash attention v8 (unchanged from round 10-12, passing) ----------------
__global__ __launch_bounds__(512, 2) void attn_kernel(const unsigned short* __restrict__ qh,
                                                      const unsigned short* __restrict__ kh,
                                                      const unsigned short* __restrict__ vt,
                                                      unsigned short* __restrict__ ctx) {
    const int t = threadIdx.x, lane = t & 63, w = t >> 6;
    const int lo = lane & 31, hi = lane >> 5;
    const int qsub = w & 3, split = w >> 2;
    const int id = blockIdx.x;
    const int g  = (id & 7) * 32 + (id >> 3);   // XCD-chunked: 4 heads per XCD
    const int by = g >> 3;                       // head-batch 0..31
    const int bx = g & 7;                        // 256-row q block 0..7
    const size_t hb = (size_t)by * (SEQ * DK);
    const int q0a = bx * 256 + qsub * 32;
    const int q0b = q0a + 128;

    struct KV { unsigned short K[2][2][64 * 64]; unsigned short V[2][2][64 * 64]; };
    struct MG { float Lo[4][2][32][64]; float Ll[4][2][64]; };
    __shared__ union SMem { KV kv; MG mg; } sm;

    const unsigned short* sp[4];
    unsigned short* dpK[4];
    int sstr[4];
#pragma unroll
    for (int i = 0; i < 4; ++i) {
        int u   = w * 4 + i;
        int isV = u >> 4;
        int ssp = (u >> 3) & 1;
        int r0  = (u & 7) * 8;
        int rl  = r0 + (lane >> 3);
        int cs  = ((lane & 7) ^ ((lane >> 3) & 7)) * 8;
        if (!isV) {
            sp[i]   = kh + hb + (size_t)(ssp * 1024 + rl) * DK + cs;
            sstr[i] = 64 * DK;
            dpK[i]  = &sm.kv.K[0][ssp][r0 * 64];
        } else {
            sp[i]   = vt + hb + (size_t)rl * SEQ + ssp * 1024 + cs;
            sstr[i] = 64;
            dpK[i]  = &sm.kv.V[0][ssp][r0 * 64];
        }
    }
    const int bufoff = 2 * 64 * 64;

    bf16x8 qfA[4], qfB[4];
#pragma unroll
    for (int tl = 0; tl < 4; ++tl) {
        qfA[tl] = ld_bf8(&qh[hb + (size_t)(q0a + lo) * DK + tl * 16 + hi * 8]);
        qfB[tl] = ld_bf8(&qh[hb + (size_t)(q0b + lo) * DK + tl * 16 + hi * 8]);
    }

    f32x16 o0a, o1a, o0b, o1b;
#pragma unroll
    for (int e = 0; e < 16; ++e) { o0a[e] = 0.f; o1a[e] = 0.f; o0b[e] = 0.f; o1b[e] = 0.f; }
    float lA = 0.f, lB = 0.f;

#pragma unroll
    for (int i = 0; i < 4; ++i) { gload16(sp[i], dpK[i]); sp[i] += sstr[i]; }
    __syncthreads();

    const int xr = lo & 7;

    for (int it = 0; it < 16; ++it) {
        const unsigned short* Kb = &sm.kv.K[it & 1][split][0];
        const unsigned short* Vb = &sm.kv.V[it & 1][split][0];
        if (it < 15) {
#pragma unroll
            for (int i = 0; i < 4; ++i) {
                unsigned short* d = dpK[i] + ((it & 1) ? 0 : bufoff);
                gload16(sp[i], d);
                sp[i] += sstr[i];
            }
        }
        // =============== STREAM A ===============
        f32x16 sA, sB;
#pragma unroll
        for (int e = 0; e < 16; ++e) { sA[e] = 0.f; sB[e] = 0.f; }
        __builtin_amdgcn_s_setprio(1);
#pragma unroll
        for (int tl = 0; tl < 4; ++tl) {
            int c = 2 * tl + hi;
            bf16x8 kfA = ld_bf8(&Kb[lo * 64 + ((c ^ xr) * 8)]);
            bf16x8 kfB = ld_bf8(&Kb[(32 + lo) * 64 + ((c ^ xr) * 8)]);
            sA = __builtin_amdgcn_mfma_f32_32x32x16_bf16(kfA, qfA[tl], sA, 0, 0, 0);
            sB = __builtin_amdgcn_mfma_f32_32x32x16_bf16(kfB, qfA[tl], sB, 0, 0, 0);
        }
        __builtin_amdgcn_s_setprio(0);
#pragma unroll
        for (int e = 0; e < 16; ++e) {
            sA[e] = __builtin_amdgcn_exp2f(sA[e]);
            sB[e] = __builtin_amdgcn_exp2f(sB[e]);
        }
        {
            float sum = tsum16(sA) + tsum16(sB);
            sum += __shfl_xor(sum, 32);
            lA += sum;
        }
        {
            uint32_t pA[8], pB[8];
#pragma unroll
            for (int i = 0; i < 8; ++i) {
                pA[i] = pkbf(sA[2 * i], sA[2 * i + 1]);
                pB[i] = pkbf(sB[2 * i], sB[2 * i + 1]);
            }
            asm volatile("v_permlane32_swap_b32 %0, %1" : "+v"(pA[0]), "+v"(pA[2]));
            asm volatile("v_permlane32_swap_b32 %0, %1" : "+v"(pA[1]), "+v"(pA[3]));
            asm volatile("v_permlane32_swap_b32 %0, %1" : "+v"(pA[4]), "+v"(pA[6]));
            asm volatile("v_permlane32_swap_b32 %0, %1" : "+v"(pA[5]), "+v"(pA[7]));
            asm volatile("v_permlane32_swap_b32 %0, %1" : "+v"(pB[0]), "+v"(pB[2]));
            asm volatile("v_permlane32_swap_b32 %0, %1" : "+v"(pB[1]), "+v"(pB[3]));
            asm volatile("v_permlane32_swap_b32 %0, %1" : "+v"(pB[4]), "+v"(pB[6]));
            asm volatile("v_permlane32_swap_b32 %0, %1" : "+v"(pB[5]), "+v"(pB[7]));
            union { uint32_t u[4]; bf16x8 v; } f0, f1, f2, f3;
            f0.u[0] = pA[0]; f0.u[1] = pA[1]; f0.u[2] = pA[2]; f0.u[3] = pA[3];
            f1.u[0] = pA[4]; f1.u[1] = pA[5]; f1.u[2] = pA[6]; f1.u[3] = pA[7];
            f2.u[0] = pB[0]; f2.u[1] = pB[1]; f2.u[2] = pB[2]; f2.u[3] = pB[3];
            f3.u[0] = pB[4]; f3.u[1] = pB[5]; f3.u[2] = pB[6]; f3.u[3] = pB[7];
            bf16x8 v00 = ld_bf8(&Vb[lo * 64 + (((0 + hi) ^ xr) * 8)]);
            bf16x8 v01 = ld_bf8(&Vb[lo * 64 + (((2 + hi) ^ xr) * 8)]);
            bf16x8 v02 = ld_bf8(&Vb[lo * 64 + (((4 + hi) ^ xr) * 8)]);
            bf16x8 v03 = ld_bf8(&Vb[lo * 64 + (((6 + hi) ^ xr) * 8)]);
            bf16x8 v10 = ld_bf8(&Vb[(32 + lo) * 64 + (((0 + hi) ^ xr) * 8)]);
            bf16x8 v11 = ld_bf8(&Vb[(32 + lo) * 64 + (((2 + hi) ^ xr) * 8)]);
            bf16x8 v12 = ld_bf8(&Vb[(32 + lo) * 64 + (((4 + hi) ^ xr) * 8)]);
            bf16x8 v13 = ld_bf8(&Vb[(32 + lo) * 64 + (((6 + hi) ^ xr) * 8)]);
            __builtin_amdgcn_s_setprio(1);
            o0a = __builtin_amdgcn_mfma_f32_32x32x16_bf16(v00, f0.v, o0a, 0, 0, 0);
            o0a = __builtin_amdgcn_mfma_f32_32x32x16_bf16(v01, f1.v, o0a, 0, 0, 0);
            o0a = __builtin_amdgcn_mfma_f32_32x32x16_bf16(v02, f2.v, o0a, 0, 0, 0);
            o0a = __builtin_amdgcn_mfma_f32_32x32x16_bf16(v03, f3.v, o0a, 0, 0, 0);
            o1a = __builtin_amdgcn_mfma_f32_32x32x16_bf16(v10, f0.v, o1a, 0, 0, 0);
            o1a = __builtin_amdgcn_mfma_f32_32x32x16_bf16(v11, f1.v, o1a, 0, 0, 0);
            o1a = __builtin_amdgcn_mfma_f32_32x32x16_bf16(v12, f2.v, o1a, 0, 0, 0);
            o1a = __builtin_amdgcn_mfma_f32_32x32x16_bf16(v13, f3.v, o1a, 0, 0, 0);
            __builtin_amdgcn_s_setprio(0);
        }
        // =============== STREAM B ===============
#pragma unroll
        for (int e = 0; e < 16; ++e) { sA[e] = 0.f; sB[e] = 0.f; }
        __builtin_amdgcn_s_setprio(1);
#pragma unroll
        for (int tl = 0; tl < 4; ++tl) {
            int c = 2 * tl + hi;
            bf16x8 kfA = ld_bf8(&Kb[lo * 64 + ((c ^ xr) * 8)]);
            bf16x8 kfB = ld_bf8(&Kb[(32 + lo) * 64 + ((c ^ xr) * 8)]);
            sA = __builtin_amdgcn_mfma_f32_32x32x16_bf16(kfA, qfB[tl], sA, 0, 0, 0);
            sB = __builtin_amdgcn_mfma_f32_32x32x16_bf16(kfB, qfB[tl], sB, 0, 0, 0);
        }
        __builtin_amdgcn_s_setprio(0);
#pragma unroll
        for (int e = 0; e < 16; ++e) {
            sA[e] = __builtin_amdgcn_exp2f(sA[e]);
            sB[e] = __builtin_amdgcn_exp2f(sB[e]);
        }
        {
            float sum = tsum16(sA) + tsum16(sB);
            sum += __shfl_xor(sum, 32);
            lB += sum;
        }
        {
            uint32_t pA[8], pB[8];
#pragma unroll
            for (int i = 0; i < 8; ++i) {
                pA[i] = pkbf(sA[2 * i], sA[2 * i + 1]);
                pB[i] = pkbf(sB[2 * i], sB[2 * i + 1]);
            }
            asm volatile("v_permlane32_swap_b32 %0, %1" : "+v"(pA[0]), "+v"(pA[2]));
            asm volatile("v_permlane32_swap_b32 %0, %1" : "+v"(pA[1]), "+v"(pA[3]));
            asm volatile("v_permlane32_swap_b32 %0, %1" : "+v"(pA[4]), "+v"(pA[6]));
            asm volatile("v_permlane32_swap_b32 %0, %1" : "+v"(pA[5]), "+v"(pA[7]));
            asm volatile("v_permlane32_swap_b32 %0, %1" : "+v"(pB[0]), "+v"(pB[2]));
            asm volatile("v_permlane32_swap_b32 %0, %1" : "+v"(pB[1]), "+v"(pB[3]));
            asm volatile("v_permlane32_swap_b32 %0, %1" : "+v"(pB[4]), "+v"(pB[6]));
            asm volatile("v_permlane32_swap_b32 %0, %1" : "+v"(pB[5]), "+v"(pB[7]));
            union { uint32_t u[4]; bf16x8 v; } f0, f1, f2, f3;
            f0.u[0] = pA[0]; f0.u[1] = pA[1]; f0.u[2] = pA[2]; f0.u[3] = pA[3];
            f1.u[0] = pA[4]; f1.u[1] = pA[5]; f1.u[2] = pA[6]; f1.u[3] = pA[7];
            f2.u[0] = pB[0]; f2.u[1] = pB[1]; f2.u[2] = pB[2]; f2.u[3] = pB[3];
            f3.u[0] = pB[4]; f3.u[1] = pB[5]; f3.u[2] = pB[6]; f3.u[3] = pB[7];
            bf16x8 v00 = ld_bf8(&Vb[lo * 64 + (((0 + hi) ^ xr) * 8)]);
            bf16x8 v01 = ld_bf8(&Vb[lo * 64 + (((2 + hi) ^ xr) * 8)]);
            bf16x8 v02 = ld_bf8(&Vb[lo * 64 + (((4 + hi) ^ xr) * 8)]);
            bf16x8 v03 = ld_bf8(&Vb[lo * 64 + (((6 + hi) ^ xr) * 8)]);
            bf16x8 v10 = ld_bf8(&Vb[(32 + lo) * 64 + (((0 + hi) ^ xr) * 8)]);
            bf16x8 v11 = ld_bf8(&Vb[(32 + lo) * 64 + (((2 + hi) ^ xr) * 8)]);
            bf16x8 v12 = ld_bf8(&Vb[(32 + lo) * 64 + (((4 + hi) ^ xr) * 8)]);
            bf16x8 v13 = ld_bf8(&Vb[(32 + lo) * 64 + (((6 + hi) ^ xr) * 8)]);
            __builtin_amdgcn_s_setprio(1);
            o0b = __builtin_amdgcn_mfma_f32_32x32x16_bf16(v00, f0.v, o0b, 0, 0, 0);
            o0b = __builtin_amdgcn_mfma_f32_32x32x16_bf16(v01, f1.v, o0b, 0, 0, 0);
            o0b = __builtin_amdgcn_mfma_f32_32x32x16_bf16(v02, f2.v, o0b, 0, 0, 0);
            o0b = __builtin_amdgcn_mfma_f32_32x32x16_bf16(v03, f3.v, o0b, 0, 0, 0);
            o1b = __builtin_amdgcn_mfma_f32_32x32x16_bf16(v10, f0.v, o1b, 0, 0, 0);
            o1b = __builtin_amdgcn_mfma_f32_32x32x16_bf16(v11, f1.v, o1b, 0, 0, 0);
            o1b = __builtin_amdgcn_mfma_f32_32x32x16_bf16(v12, f2.v, o1b, 0, 0, 0);
            o1b = __builtin_amdgcn_mfma_f32_32x32x16_bf16(v13, f3.v, o1b, 0, 0, 0);
            __builtin_amdgcn_s_setprio(0);
        }
        __syncthreads();
    }

    if (split == 1) {
#pragma unroll
        for (int e = 0; e < 16; ++e) {
            sm.mg.Lo[qsub][0][e][lane]      = o0a[e];
            sm.mg.Lo[qsub][0][16 + e][lane] = o1a[e];
            sm.mg.Lo[qsub][1][e][lane]      = o0b[e];
            sm.mg.Lo[qsub][1][16 + e][lane] = o1b[e];
        }
        sm.mg.Ll[qsub][0][lane] = lA;
        sm.mg.Ll[qsub][1][lane] = lB;
    }
    __syncthreads();
    if (split == 0) {
        const int b = by >> 4, hd = by & 15;
        {
            float rl = __builtin_amdgcn_rcpf(lA + sm.mg.Ll[qsub][0][lane]);
            unsigned short* orow = ctx + ((size_t)(b * SEQ + q0a + lo)) * HIDDEN + hd * 64;
#pragma unroll
            for (int dt = 0; dt < 2; ++dt) {
#pragma unroll
                for (int gq = 0; gq < 4; ++gq) {
                    union { unsigned short us[4]; uint2 v; } pk;
#pragma unroll
                    for (int c = 0; c < 4; ++c) {
                        int e = gq * 4 + c;
                        float own = dt ? o1a[e] : o0a[e];
                        float oth = sm.mg.Lo[qsub][0][dt * 16 + e][lane];
                        pk.us[c] = f2bf((own + oth) * rl);
                    }
                    *reinterpret_cast<uint2*>(orow + dt * 32 + gq * 8 + hi * 4) = pk.v;
                }
            }
        }
        {
            float rl = __builtin_amdgcn_rcpf(lB + sm.mg.Ll[qsub][1][lane]);
            unsigned short* orow = ctx + ((size_t)(b * SEQ + q0b + lo)) * HIDDEN + hd * 64;
#pragma unroll
            for (int dt = 0; dt < 2; ++dt) {
#pragma unroll
                for (int gq = 0; gq < 4; ++gq) {
                    union { unsigned short us[4]; uint2 v; } pk;
#pragma unroll
                    for (int c = 0; c < 4; ++c) {
                        int e = gq * 4 + c;
                        float own = dt ? o1b[e] : o0b[e];
                        float oth = sm.mg.Lo[qsub][1][dt * 16 + e][lane];
                        pk.us[c] = f2bf((own + oth) * rl);
                    }
                    *reinterpret_cast<uint2*>(orow + dt * 32 + gq * 8 + hi * 4) = pk.v;
                }
            }
        }
    }
}

// ---------------- launch ----------------
extern "C" void kernel_launch(void* const* d_in, const int* in_sizes, int n_in,
                              void* d_out, int out_size, void* d_ws, size_t ws_size,
                              hipStream_t stream) {
    const float* q  = (const float*)d_in[0];
    const float* k  = (const float*)d_in[1];
    const float* v  = (const float*)d_in[2];
    const float* Wq = (const float*)d_in[3];
    const float* bq = (const float*)d_in[4];
    const float* Wk = (const float*)d_in[5];
    const float* bk = (const float*)d_in[6];
    const float* Wv = (const float*)d_in[7];
    const float* bv = (const float*)d_in[8];
    const float* Wo = (const float*)d_in[9];
    const float* bo = (const float*)d_in[10];

    unsigned short* qbf = (unsigned short*)d_ws;
    unsigned short* kbf = qbf + (size_t)MTOT * HIDDEN;
    unsigned short* vbf = kbf + (size_t)MTOT * HIDDEN;
    unsigned short* wqb = vbf + (size_t)MTOT * HIDDEN;
    unsigned short* wkb = wqb + (size_t)HIDDEN * HIDDEN;
    unsigned short* wvb = wkb + (size_t)HIDDEN * HIDDEN;
    unsigned short* wob = wvb + (size_t)HIDDEN * HIDDEN;
    unsigned short* qh  = wob + (size_t)HIDDEN * HIDDEN;
    unsigned short* kh  = qh + (size_t)MTOT * HIDDEN;
    unsigned short* vt  = kh + (size_t)MTOT * HIDDEN;
    unsigned short* ctx = vt + (size_t)MTOT * HIDDEN;

    const int nAct8 = MTOT * HIDDEN / 8;    // 524288
    const int nW8   = HIDDEN * HIDDEN / 8;  // 131072

    Cvt7 ca;
    ca.s[0] = q;  ca.d[0] = qbf; ca.n8[0] = nAct8;
    ca.s[1] = k;  ca.d[1] = kbf; ca.n8[1] = nAct8;
    ca.s[2] = v;  ca.d[2] = vbf; ca.n8[2] = nAct8;
    ca.s[3] = Wq; ca.d[3] = wqb; ca.n8[3] = nW8;
    ca.s[4] = Wk; ca.d[4] = wkb; ca.n8[4] = nW8;
    ca.s[5] = Wv; ca.d[5] = wvb; ca.n8[5] = nW8;
    ca.s[6] = Wo; ca.d[6] = wob; ca.n8[6] = nW8;
    cvt_all<<<dim3(nAct8 / 256, 7), dim3(256), 0, stream>>>(ca);

    gemm_qkv<<<dim3(HIDDEN / 128, MTOT / 128, 3), dim3(256), 0, stream>>>(
        qbf, kbf, vbf, wqb, wkb, wvb, bq, bk, bv, qh, kh, vt);

    attn_kernel<<<dim3(256), dim3(512), 0, stream>>>(qh, kh, vt, ctx);

    gemm_out<<<dim3(HIDDEN / 128, MTOT / 128), dim3(256), 0, stream>>>(
        ctx, wob, bo, (float*)d_out);
}